// Round 3
// baseline (559.083 us; speedup 1.0000x reference)
//
#include <hip/hip_runtime.h>
#include <stdint.h>

typedef __attribute__((ext_vector_type(8))) short short8;
typedef __attribute__((ext_vector_type(4))) float floatx4;

#define TLEN 2048
#define BATCH 4
#define EMB 2048
#define NHEADS 16
#define HDIM 128
#define MROWS (BATCH * TLEN) /* 8192 */
#define QTILES (TLEN / 64)   /* 32 */

__device__ __forceinline__ ushort f2bf(float f) {
    union { float f; uint32_t u; } v; v.f = f;
    uint32_t u = v.u;
    return (ushort)((u + 0x7fffu + ((u >> 16) & 1u)) >> 16);
}

__device__ __forceinline__ uint32_t cvt_pk_bf16(float a, float b) {
    uint32_t r;
    asm volatile("v_cvt_pk_bf16_f32 %0, %1, %2" : "=v"(r) : "v"(a), "v"(b));
    return r;
}

__device__ __forceinline__ void async_copy16(const ushort* g, ushort* l) {
    __builtin_amdgcn_global_load_lds(
        (const __attribute__((address_space(1))) uint32_t*)g,
        (__attribute__((address_space(3))) uint32_t*)l, 16, 0, 0);
}

// ---------------- cast fp32 -> bf16 ----------------
__global__ __launch_bounds__(256) void cast_bf16_kernel(const float* __restrict__ in,
                                                        ushort* __restrict__ out, int n) {
    int i = (blockIdx.x * 256 + threadIdx.x) * 4;
    if (i >= n) return;
    float4 f = *(const float4*)(in + i);
    ushort4 o;
    o.x = f2bf(f.x); o.y = f2bf(f.y); o.z = f2bf(f.z); o.w = f2bf(f.w);
    *(ushort4*)(out + i) = o;
}

// ---------------- transpose + cast: fp32 [R][Cc] -> bf16 [Cc][R] ----------------
__global__ void transpose_cast_kernel(const float* __restrict__ in, ushort* __restrict__ out,
                                      int R, int Cc) {
    __shared__ float tile[32][33];
    int x = blockIdx.x * 32 + threadIdx.x;
    int y0 = blockIdx.y * 32;
#pragma unroll
    for (int i = 0; i < 4; i++) {
        int y = y0 + threadIdx.y + i * 8;
        tile[threadIdx.y + i * 8][threadIdx.x] = in[(size_t)y * Cc + x];
    }
    __syncthreads();
    int xo = y0 + threadIdx.x;
#pragma unroll
    for (int i = 0; i < 4; i++) {
        int yo = blockIdx.x * 32 + threadIdx.y + i * 8;
        out[(size_t)yo * R + xo] = f2bf(tile[threadIdx.x][threadIdx.y + i * 8]);
    }
}

// ---------------- bf16 MFMA GEMM (m97 structure): C = A[M,K] * Bt[N,K]^T ----------------
// XCD-chunked blockIdx swizzle (T1): each XCD gets a contiguous run of row-panels -> A L2 reuse.
// All grids here have nwg % 8 == 0 so the simple bijective form is valid.
template <int MODE>
__global__ __launch_bounds__(256) void gemm_bt_kernel(const ushort* __restrict__ A,
                                                      const ushort* __restrict__ Bt,
                                                      void* __restrict__ Cp,
                                                      void* __restrict__ Cp2,
                                                      const float* __restrict__ bias,
                                                      int M, int N, int K) {
    __shared__ ushort As[128 * 64];
    __shared__ ushort Bs[128 * 64];
    int tid = threadIdx.x;
    int wid = tid >> 6, lane = tid & 63;
    int quad = lane >> 4, l15 = lane & 15;

    int nwg = gridDim.x * gridDim.y;
    int wg = blockIdx.y * gridDim.x + blockIdx.x;
    int cpx = nwg >> 3;
    int swz = (wg & 7) * cpx + (wg >> 3);
    int bx = swz % gridDim.x, by = swz / gridDim.x;

    int m0 = by * 128;
    int n0 = bx * 128;
    int rm = (wid >> 1) * 64;
    int cn = (wid & 1) * 64;
    int grow = lane >> 3;       // 0..7
    int gcol = (lane & 7) * 8;  // 0..56

    floatx4 acc[4][4];
#pragma unroll
    for (int i = 0; i < 4; i++)
#pragma unroll
        for (int j = 0; j < 4; j++)
#pragma unroll
            for (int r = 0; r < 4; r++) acc[i][j][r] = 0.f;

    for (int kk = 0; kk < K; kk += 64) {
#pragma unroll
        for (int c = 0; c < 4; c++) {
            int chunk = wid * 4 + c;              // 0..15, wave-uniform
            int row = chunk * 8 + grow;
            async_copy16(A + (size_t)(m0 + row) * K + kk + gcol, &As[chunk * 512]);
            async_copy16(Bt + (size_t)(n0 + row) * K + kk + gcol, &Bs[chunk * 512]);
        }
        __syncthreads();
#pragma unroll
        for (int ks = 0; ks < 64; ks += 32) {
            short8 af[4], bf[4];
#pragma unroll
            for (int i = 0; i < 4; i++)
                af[i] = *(const short8*)(&As[(rm + i * 16 + l15) * 64 + ks + quad * 8]);
#pragma unroll
            for (int j = 0; j < 4; j++)
                bf[j] = *(const short8*)(&Bs[(cn + j * 16 + l15) * 64 + ks + quad * 8]);
#pragma unroll
            for (int i = 0; i < 4; i++)
#pragma unroll
                for (int j = 0; j < 4; j++)
                    acc[i][j] = __builtin_amdgcn_mfma_f32_16x16x32_bf16(af[i], bf[j], acc[i][j], 0, 0, 0);
        }
        __syncthreads();
    }
#pragma unroll
    for (int i = 0; i < 4; i++)
#pragma unroll
        for (int j = 0; j < 4; j++) {
            if (MODE == 2 && n0 != 0) {
                int d = cn + j * 16 + l15;
                int row = m0 + rm + i * 16 + quad * 4;
                ushort4 o;
                o.x = f2bf(acc[i][j][0]); o.y = f2bf(acc[i][j][1]);
                o.z = f2bf(acc[i][j][2]); o.w = f2bf(acc[i][j][3]);
                *(ushort4*)((ushort*)Cp2 + (size_t)d * M + row) = o;
            } else {
#pragma unroll
                for (int r = 0; r < 4; r++) {
                    int row = m0 + rm + i * 16 + quad * 4 + r;
                    int col = n0 + cn + j * 16 + l15;
                    float v = acc[i][j][r];
                    if (MODE == 0) {
                        ((ushort*)Cp)[(size_t)row * N + col] = f2bf(v);
                    } else if (MODE == 1) {
                        ((float*)Cp)[(size_t)row * N + col] = v + bias[col];
                    } else {
                        ((ushort*)Cp)[(size_t)row * HDIM + col] = f2bf(v);
                    }
                }
            }
        }
}

// ---------------- flash MQA attention: 1 q-tile/block, 2 heads, P in registers, KVBLK=128 ----
// grid: (QTILES, H/2, B) = 1024 blocks. LDS 64KB -> 2 blocks/CU; KVBLK=128 halves the number
// of stage/vmcnt-drain/barrier events and doubles MFMA per staged tile (128/wave-iter).
// K/V staged via swizzled global_load_lds (linear LDS + pre-swizzled source, col ^= (row&7)<<3).
// Swapped QK^T + permlane32/16_swap assembles PV A-frags fully in-register (no P LDS).
__global__ __launch_bounds__(256, 2) void mqa_attn_kernel(const ushort* __restrict__ Qb,
                                                          const ushort* __restrict__ Kb,
                                                          const ushort* __restrict__ Vg,
                                                          ushort* __restrict__ Ab) {
    __shared__ ushort Ks[128 * 128];   // [key][d], XOR-swizzled cols (32KB)
    __shared__ ushort Vs[128 * 128];   // V^T [d][key], XOR-swizzled cols (32KB)
    int tid = threadIdx.x;
    int wid = tid >> 6, lane = tid & 63;
    int quad = lane >> 4, l15 = lane & 15;
    int h0 = blockIdx.y * 2, b = blockIdx.z;
    int qt = (QTILES - 1) - blockIdx.x;   // longest blocks dispatched first
    const float scale2 = 0.08838834764831845f * 1.4426950408889634f; // 1/sqrt(128)*log2(e)
    const ushort* kbase = Kb + (size_t)b * TLEN * HDIM;
    const ushort* vbase = Vg + (size_t)b * TLEN;
    size_t qrowbase = (size_t)b * TLEN + qt * 64;

    // Q fragments in registers (reused across all jt)
    short8 aq[2][4];
#pragma unroll
    for (int hh = 0; hh < 2; hh++) {
        const ushort* qp = Qb + (qrowbase + wid * 16 + l15) * EMB + (h0 + hh) * HDIM + quad * 8;
#pragma unroll
        for (int kd = 0; kd < 4; kd++) aq[hh][kd] = *(const short8*)(qp + kd * 32);
    }

    float lsum[2] = {0.f, 0.f};
    floatx4 o_acc[2][8];
#pragma unroll
    for (int hh = 0; hh < 2; hh++)
#pragma unroll
        for (int nd = 0; nd < 8; nd++)
#pragma unroll
            for (int r = 0; r < 4; r++) o_acc[hh][nd][r] = 0.f;

    int rowloc = wid * 16 + l15;            // q-row within the 64-row q-tile
    int dlim = rowloc + ((qt & 1) ? 64 : 0); // diag-tile local key limit
    int swz = (l15 & 7) << 3;
    int njt = qt / 2 + 1;                   // number of 128-key tiles
    bool evenqt = (qt & 1) == 0;

#pragma unroll 1
    for (int jt = 0; jt < njt; ++jt) {
        // ---- stage K/V 128-key tile via global_load_lds, swizzled source ----
#pragma unroll
        for (int i = 0; i < 8; i++) {
            int c = wid * 8 + i;                             // chunk 0..31 (1KB each)
            int kr = c * 4 + (lane >> 4);                    // K row in tile 0..127
            int kc = ((lane & 15) * 8) ^ ((kr & 7) << 3);    // swizzled ushort col
            async_copy16(kbase + (size_t)(jt * 128 + kr) * HDIM + kc, &Ks[c * 512]);
            int vd = c * 4 + (lane >> 4);                    // V d-row 0..127
            int vc = ((lane & 15) * 8) ^ ((vd & 7) << 3);    // swizzled ushort col
            async_copy16(vbase + (size_t)vd * MROWS + jt * 128 + vc, &Vs[c * 512]);
        }
        __syncthreads();   // drains vmcnt: all gload_lds landed

        bool diag = (jt == njt - 1);
#pragma unroll
        for (int jp = 0; jp < 4; jp++) {     // key chunk of 32: j in {2jp, 2jp+1}
            if (diag && evenqt && jp >= 2) continue;  // upper half fully masked
            uint32_t XA[2][2], XB[2][2];     // [hh][jj] packed bf16 pairs
#pragma unroll
            for (int jj = 0; jj < 2; jj++) {
                int j = jp * 2 + jj;
                floatx4 s0, s1;
#pragma unroll
                for (int r = 0; r < 4; r++) { s0[r] = 0.f; s1[r] = 0.f; }
                __builtin_amdgcn_s_setprio(1);
#pragma unroll
                for (int kd = 0; kd < 4; kd++) {
                    short8 ak = *(const short8*)(&Ks[(j * 16 + l15) * 128 + ((kd * 32 + quad * 8) ^ swz)]);
                    s0 = __builtin_amdgcn_mfma_f32_16x16x32_bf16(ak, aq[0][kd], s0, 0, 0, 0);
                    s1 = __builtin_amdgcn_mfma_f32_16x16x32_bf16(ak, aq[1][kd], s1, 0, 0, 0);
                }
                __builtin_amdgcn_s_setprio(0);
                // softmax (fixed-max): e = exp2(s*scale2), causal mask, per-lane row partials
                float e0[4], e1[4];
#pragma unroll
                for (int r = 0; r < 4; r++) {
                    int key = j * 16 + quad * 4 + r;
                    float v0 = exp2f(s0[r] * scale2);
                    float v1 = exp2f(s1[r] * scale2);
                    if (diag && key > dlim) { v0 = 0.f; v1 = 0.f; }
                    e0[r] = v0; e1[r] = v1;
                    lsum[0] += v0; lsum[1] += v1;
                }
                XA[0][jj] = cvt_pk_bf16(e0[0], e0[1]); XB[0][jj] = cvt_pk_bf16(e0[2], e0[3]);
                XA[1][jj] = cvt_pk_bf16(e1[0], e1[1]); XB[1][jj] = cvt_pk_bf16(e1[2], e1[3]);
            }
            // ---- cross-quad redistribution -> PV A-fragments (in-register) ----
            short8 pf[2];
#pragma unroll
            for (int hh = 0; hh < 2; hh++) {
                uint32_t xA = XA[hh][0], yA = XA[hh][1];
                uint32_t xB = XB[hh][0], yB = XB[hh][1];
                asm volatile("v_permlane32_swap_b32 %0, %1" : "+v"(xA), "+v"(yA));
                asm volatile("v_permlane16_swap_b32 %0, %1" : "+v"(xA), "+v"(yA));
                asm volatile("v_permlane32_swap_b32 %0, %1" : "+v"(xB), "+v"(yB));
                asm volatile("v_permlane16_swap_b32 %0, %1" : "+v"(xB), "+v"(yB));
                union { uint32_t u[4]; short8 s; } fu;
                fu.u[0] = xA; fu.u[1] = xB; fu.u[2] = yA; fu.u[3] = yB;
                pf[hh] = fu.s;
            }
            // ---- O += P V for this 32-key chunk ----
            __builtin_amdgcn_s_setprio(1);
#pragma unroll
            for (int nd = 0; nd < 8; nd++) {
                short8 vf = *(const short8*)(&Vs[(nd * 16 + l15) * 128 + ((jp * 32 + quad * 8) ^ swz)]);
                o_acc[0][nd] = __builtin_amdgcn_mfma_f32_16x16x32_bf16(pf[0], vf, o_acc[0][nd], 0, 0, 0);
                o_acc[1][nd] = __builtin_amdgcn_mfma_f32_16x16x32_bf16(pf[1], vf, o_acc[1][nd], 0, 0, 0);
            }
            __builtin_amdgcn_s_setprio(0);
        }
        __syncthreads();   // all reads done before next tile overwrites LDS
    }

    // row sums: lane holds partial for q-row l15; reduce across quads, then gather
    // the 4 rows (quad*4+r) this lane's o_acc covers via width-16 shfl.
#pragma unroll
    for (int hh = 0; hh < 2; hh++) {
        float ls = lsum[hh];
        ls += __shfl_xor(ls, 16);
        ls += __shfl_xor(ls, 32);
        float inv_l[4];
#pragma unroll
        for (int r = 0; r < 4; r++) inv_l[r] = 1.f / __shfl(ls, quad * 4 + r, 16);
#pragma unroll
        for (int nd = 0; nd < 8; nd++)
#pragma unroll
            for (int r = 0; r < 4; r++) {
                size_t row = qrowbase + wid * 16 + quad * 4 + r;
                int col = (h0 + hh) * HDIM + nd * 16 + l15;
                Ab[row * EMB + col] = f2bf(o_acc[hh][nd][r] * inv_l[r]);
            }
    }
}

extern "C" void kernel_launch(void* const* d_in, const int* in_sizes, int n_in,
                              void* d_out, int out_size, void* d_ws, size_t ws_size,
                              hipStream_t stream) {
    const float* x  = (const float*)d_in[0];
    const float* Wq = (const float*)d_in[1];
    const float* Wk = (const float*)d_in[2];
    const float* Wv = (const float*)d_in[3];
    const float* Wo = (const float*)d_in[4];
    const float* bo = (const float*)d_in[5];
    float* out = (float*)d_out;

    ushort* ws = (ushort*)d_ws;
    ushort* Xb    = ws;                              // [8192][2048]
    ushort* Wq_t  = Xb    + (size_t)MROWS * EMB;     // [2048][2048]
    ushort* Wkv_t = Wq_t  + (size_t)EMB * EMB;       // [256][2048]
    ushort* Wo_t  = Wkv_t + (size_t)256 * EMB;       // [2048][2048]
    ushort* Qb    = Wo_t  + (size_t)EMB * EMB;       // [8192][2048]
    ushort* Kb    = Qb    + (size_t)MROWS * EMB;     // [8192][128]
    ushort* Vg    = Kb    + (size_t)MROWS * HDIM;    // V^T [128][8192]
    ushort* Ab    = Vg    + (size_t)HDIM * MROWS;    // [8192][2048]

    cast_bf16_kernel<<<dim3(MROWS * EMB / 1024), 256, 0, stream>>>(x, Xb, MROWS * EMB);
    transpose_cast_kernel<<<dim3(EMB / 32, EMB / 32), dim3(32, 8), 0, stream>>>(Wq, Wq_t, EMB, EMB);
    transpose_cast_kernel<<<dim3(HDIM / 32, EMB / 32), dim3(32, 8), 0, stream>>>(Wk, Wkv_t, EMB, HDIM);
    transpose_cast_kernel<<<dim3(HDIM / 32, EMB / 32), dim3(32, 8), 0, stream>>>(Wv, Wkv_t + (size_t)HDIM * EMB, EMB, HDIM);
    transpose_cast_kernel<<<dim3(EMB / 32, EMB / 32), dim3(32, 8), 0, stream>>>(Wo, Wo_t, EMB, EMB);

    gemm_bt_kernel<0><<<dim3(EMB / 128, MROWS / 128), 256, 0, stream>>>(Xb, Wq_t, Qb, nullptr, nullptr, MROWS, EMB, EMB);
    gemm_bt_kernel<2><<<dim3(2, MROWS / 128), 256, 0, stream>>>(Xb, Wkv_t, Kb, Vg, nullptr, MROWS, 256, EMB);
    mqa_attn_kernel<<<dim3(QTILES, NHEADS / 2, BATCH), 256, 0, stream>>>(Qb, Kb, Vg, Ab);
    gemm_bt_kernel<1><<<dim3(EMB / 128, MROWS / 128), 256, 0, stream>>>(Ab, Wo_t, out, nullptr, bo, MROWS, EMB, EMB);
}

// Round 4
// 555.020 us; speedup vs baseline: 1.0073x; 1.0073x over previous
//
#include <hip/hip_runtime.h>
#include <stdint.h>

typedef __attribute__((ext_vector_type(8))) short short8;
typedef __attribute__((ext_vector_type(4))) float floatx4;

#define TLEN 2048
#define BATCH 4
#define EMB 2048
#define NHEADS 16
#define HDIM 128
#define MROWS (BATCH * TLEN) /* 8192 */
#define QTILES (TLEN / 64)   /* 32 */

__device__ __forceinline__ ushort f2bf(float f) {
    union { float f; uint32_t u; } v; v.f = f;
    uint32_t u = v.u;
    return (ushort)((u + 0x7fffu + ((u >> 16) & 1u)) >> 16);
}

__device__ __forceinline__ uint32_t cvt_pk_bf16(float a, float b) {
    uint32_t r;
    asm volatile("v_cvt_pk_bf16_f32 %0, %1, %2" : "=v"(r) : "v"(a), "v"(b));
    return r;
}

__device__ __forceinline__ void async_copy16(const ushort* g, ushort* l) {
    __builtin_amdgcn_global_load_lds(
        (const __attribute__((address_space(1))) uint32_t*)g,
        (__attribute__((address_space(3))) uint32_t*)l, 16, 0, 0);
}

// ---------------- cast fp32 -> bf16 ----------------
__global__ __launch_bounds__(256) void cast_bf16_kernel(const float* __restrict__ in,
                                                        ushort* __restrict__ out, int n) {
    int i = (blockIdx.x * 256 + threadIdx.x) * 4;
    if (i >= n) return;
    float4 f = *(const float4*)(in + i);
    ushort4 o;
    o.x = f2bf(f.x); o.y = f2bf(f.y); o.z = f2bf(f.z); o.w = f2bf(f.w);
    *(ushort4*)(out + i) = o;
}

// ---------------- transpose + cast: fp32 [R][Cc] -> bf16 [Cc][R] ----------------
__global__ void transpose_cast_kernel(const float* __restrict__ in, ushort* __restrict__ out,
                                      int R, int Cc) {
    __shared__ float tile[32][33];
    int x = blockIdx.x * 32 + threadIdx.x;
    int y0 = blockIdx.y * 32;
#pragma unroll
    for (int i = 0; i < 4; i++) {
        int y = y0 + threadIdx.y + i * 8;
        tile[threadIdx.y + i * 8][threadIdx.x] = in[(size_t)y * Cc + x];
    }
    __syncthreads();
    int xo = y0 + threadIdx.x;
#pragma unroll
    for (int i = 0; i < 4; i++) {
        int yo = blockIdx.x * 32 + threadIdx.y + i * 8;
        out[(size_t)yo * R + xo] = f2bf(tile[threadIdx.x][threadIdx.y + i * 8]);
    }
}

// ---------------- bf16 MFMA GEMM (m97 structure): C = A[M,K] * Bt[N,K]^T ----------------
// Default blockIdx mapping: at N=2048 each XCD naturally sees only 2 B col-panels (1MB,
// L2-resident). XCD-chunked swizzle measurably regressed this (round 3): do not swizzle.
template <int MODE>
__global__ __launch_bounds__(256) void gemm_bt_kernel(const ushort* __restrict__ A,
                                                      const ushort* __restrict__ Bt,
                                                      void* __restrict__ Cp,
                                                      void* __restrict__ Cp2,
                                                      const float* __restrict__ bias,
                                                      int M, int N, int K) {
    __shared__ ushort As[128 * 64];
    __shared__ ushort Bs[128 * 64];
    int tid = threadIdx.x;
    int wid = tid >> 6, lane = tid & 63;
    int quad = lane >> 4, l15 = lane & 15;
    int m0 = blockIdx.y * 128;
    int n0 = blockIdx.x * 128;
    int rm = (wid >> 1) * 64;
    int cn = (wid & 1) * 64;
    int grow = lane >> 3;       // 0..7
    int gcol = (lane & 7) * 8;  // 0..56

    floatx4 acc[4][4];
#pragma unroll
    for (int i = 0; i < 4; i++)
#pragma unroll
        for (int j = 0; j < 4; j++)
#pragma unroll
            for (int r = 0; r < 4; r++) acc[i][j][r] = 0.f;

    for (int kk = 0; kk < K; kk += 64) {
#pragma unroll
        for (int c = 0; c < 4; c++) {
            int chunk = wid * 4 + c;              // 0..15, wave-uniform
            int row = chunk * 8 + grow;
            async_copy16(A + (size_t)(m0 + row) * K + kk + gcol, &As[chunk * 512]);
            async_copy16(Bt + (size_t)(n0 + row) * K + kk + gcol, &Bs[chunk * 512]);
        }
        __syncthreads();
#pragma unroll
        for (int ks = 0; ks < 64; ks += 32) {
            short8 af[4], bf[4];
#pragma unroll
            for (int i = 0; i < 4; i++)
                af[i] = *(const short8*)(&As[(rm + i * 16 + l15) * 64 + ks + quad * 8]);
#pragma unroll
            for (int j = 0; j < 4; j++)
                bf[j] = *(const short8*)(&Bs[(cn + j * 16 + l15) * 64 + ks + quad * 8]);
#pragma unroll
            for (int i = 0; i < 4; i++)
#pragma unroll
                for (int j = 0; j < 4; j++)
                    acc[i][j] = __builtin_amdgcn_mfma_f32_16x16x32_bf16(af[i], bf[j], acc[i][j], 0, 0, 0);
        }
        __syncthreads();
    }
#pragma unroll
    for (int i = 0; i < 4; i++)
#pragma unroll
        for (int j = 0; j < 4; j++) {
            if (MODE == 2 && n0 != 0) {
                int d = cn + j * 16 + l15;
                int row = m0 + rm + i * 16 + quad * 4;
                ushort4 o;
                o.x = f2bf(acc[i][j][0]); o.y = f2bf(acc[i][j][1]);
                o.z = f2bf(acc[i][j][2]); o.w = f2bf(acc[i][j][3]);
                *(ushort4*)((ushort*)Cp2 + (size_t)d * M + row) = o;
            } else {
#pragma unroll
                for (int r = 0; r < 4; r++) {
                    int row = m0 + rm + i * 16 + quad * 4 + r;
                    int col = n0 + cn + j * 16 + l15;
                    float v = acc[i][j][r];
                    if (MODE == 0) {
                        ((ushort*)Cp)[(size_t)row * N + col] = f2bf(v);
                    } else if (MODE == 1) {
                        ((float*)Cp)[(size_t)row * N + col] = v + bias[col];
                    } else {
                        ((ushort*)Cp)[(size_t)row * HDIM + col] = f2bf(v);
                    }
                }
            }
        }
}

// ---------------- flash MQA attention: 1 q-tile/block, 2 heads, P in registers ----------------
// grid: (QTILES, H/2, B) = 1024 blocks, 2 blocks/CU (64KB LDS).
// KVBLK=64, DOUBLE-BUFFERED (T3 minimum 2-phase): issue gload_lds for tile t+1 into the
// other buffer BEFORE computing tile t, so the compiler's vmcnt(0) drain (before the
// end-of-iter barrier) lands after the compute phase -> prefetch latency hides under
// the 64 MFMA + softmax of the current tile.
// K/V staged via swizzled global_load_lds (linear LDS + pre-swizzled source col^=(row&7)*8).
// Swapped QK^T + permlane32/16_swap assembles PV A-frags fully in-register (no P LDS).
__global__ __launch_bounds__(256, 2) void mqa_attn_kernel(const ushort* __restrict__ Qb,
                                                          const ushort* __restrict__ Kb,
                                                          const ushort* __restrict__ Vg,
                                                          ushort* __restrict__ Ab) {
    __shared__ ushort Ks[2][64 * 128];   // [buf][key][d], XOR-swizzled cols (16KB each)
    __shared__ ushort Vs[2][64 * 128];   // [buf] V^T [d][key], XOR-swizzled cols (16KB each)
    int tid = threadIdx.x;
    int wid = tid >> 6, lane = tid & 63;
    int quad = lane >> 4, l15 = lane & 15;
    int h0 = blockIdx.y * 2, b = blockIdx.z;
    int qt = (QTILES - 1) - blockIdx.x;   // longest blocks dispatched first
    const float scale2 = 0.08838834764831845f * 1.4426950408889634f; // 1/sqrt(128)*log2(e)
    const ushort* kbase = Kb + (size_t)b * TLEN * HDIM;
    const ushort* vbase = Vg + (size_t)b * TLEN;
    size_t qrowbase = (size_t)b * TLEN + qt * 64;

    // Q fragments in registers (reused across all jt)
    short8 aq[2][4];
#pragma unroll
    for (int hh = 0; hh < 2; hh++) {
        const ushort* qp = Qb + (qrowbase + wid * 16 + l15) * EMB + (h0 + hh) * HDIM + quad * 8;
#pragma unroll
        for (int kd = 0; kd < 4; kd++) aq[hh][kd] = *(const short8*)(qp + kd * 32);
    }

    float lsum[2] = {0.f, 0.f};
    floatx4 o_acc[2][8];
#pragma unroll
    for (int hh = 0; hh < 2; hh++)
#pragma unroll
        for (int nd = 0; nd < 8; nd++)
#pragma unroll
            for (int r = 0; r < 4; r++) o_acc[hh][nd][r] = 0.f;

    int rowloc = wid * 16 + l15;   // q-row within the 64-row q-tile
    int swz = (l15 & 7) << 3;

    // ---- staging: one 64-key K tile (16KB) + one 64-key V^T tile (16KB), swizzled src ----
    auto stage = [&](int buf, int jt) {
#pragma unroll
        for (int i = 0; i < 4; i++) {
            int c = wid * 4 + i;                             // chunk 0..15 (1KB each)
            int kr = c * 4 + (lane >> 4);                    // K row in tile 0..63
            int kc = ((lane & 15) * 8) ^ ((kr & 7) << 3);    // swizzled ushort col
            async_copy16(kbase + (size_t)(jt * 64 + kr) * HDIM + kc, &Ks[buf][c * 512]);
            int vd = c * 8 + (lane >> 3);                    // V d-row 0..127 (2 rows per 1KB.. 8/chunk)
            int vc = ((lane & 7) * 8) ^ ((lane >> 3) << 3);  // swizzled ushort col (vd&7 == lane>>3)
            async_copy16(vbase + (size_t)vd * MROWS + jt * 64 + vc, &Vs[buf][c * 512]);
        }
    };

    stage(0, 0);
    __syncthreads();   // prologue drain

#pragma unroll 1
    for (int jt = 0; jt <= qt; ++jt) {
        int cur = jt & 1;
        if (jt < qt) stage(cur ^ 1, jt + 1);   // issue next-tile loads FIRST (overlap compute)
        bool diag = (jt == qt);
        const ushort* Kc = &Ks[cur][0];
        const ushort* Vc = &Vs[cur][0];
#pragma unroll
        for (int jp = 0; jp < 2; jp++) {     // key chunk of 32: j in {2jp, 2jp+1}
            uint32_t XA[2][2], XB[2][2];     // [hh][jj] packed bf16 pairs
#pragma unroll
            for (int jj = 0; jj < 2; jj++) {
                int j = jp * 2 + jj;
                floatx4 s0, s1;
#pragma unroll
                for (int r = 0; r < 4; r++) { s0[r] = 0.f; s1[r] = 0.f; }
                __builtin_amdgcn_s_setprio(1);
#pragma unroll
                for (int kd = 0; kd < 4; kd++) {
                    short8 ak = *(const short8*)(&Kc[(j * 16 + l15) * 128 + ((kd * 32 + quad * 8) ^ swz)]);
                    s0 = __builtin_amdgcn_mfma_f32_16x16x32_bf16(ak, aq[0][kd], s0, 0, 0, 0);
                    s1 = __builtin_amdgcn_mfma_f32_16x16x32_bf16(ak, aq[1][kd], s1, 0, 0, 0);
                }
                __builtin_amdgcn_s_setprio(0);
                // softmax (fixed-max): e = exp2(s*scale2), causal mask, per-lane row partials
                float e0[4], e1[4];
#pragma unroll
                for (int r = 0; r < 4; r++) {
                    int key = j * 16 + quad * 4 + r;
                    float v0 = exp2f(s0[r] * scale2);
                    float v1 = exp2f(s1[r] * scale2);
                    if (diag && key > rowloc) { v0 = 0.f; v1 = 0.f; }
                    e0[r] = v0; e1[r] = v1;
                    lsum[0] += v0; lsum[1] += v1;
                }
                XA[0][jj] = cvt_pk_bf16(e0[0], e0[1]); XB[0][jj] = cvt_pk_bf16(e0[2], e0[3]);
                XA[1][jj] = cvt_pk_bf16(e1[0], e1[1]); XB[1][jj] = cvt_pk_bf16(e1[2], e1[3]);
            }
            // ---- cross-quad redistribution -> PV A-fragments (in-register) ----
            short8 pf[2];
#pragma unroll
            for (int hh = 0; hh < 2; hh++) {
                uint32_t xA = XA[hh][0], yA = XA[hh][1];
                uint32_t xB = XB[hh][0], yB = XB[hh][1];
                asm volatile("v_permlane32_swap_b32 %0, %1" : "+v"(xA), "+v"(yA));
                asm volatile("v_permlane16_swap_b32 %0, %1" : "+v"(xA), "+v"(yA));
                asm volatile("v_permlane32_swap_b32 %0, %1" : "+v"(xB), "+v"(yB));
                asm volatile("v_permlane16_swap_b32 %0, %1" : "+v"(xB), "+v"(yB));
                union { uint32_t u[4]; short8 s; } fu;
                fu.u[0] = xA; fu.u[1] = xB; fu.u[2] = yA; fu.u[3] = yB;
                pf[hh] = fu.s;
            }
            // ---- O += P V for this 32-key chunk ----
            __builtin_amdgcn_s_setprio(1);
#pragma unroll
            for (int nd = 0; nd < 8; nd++) {
                short8 vf = *(const short8*)(&Vc[(nd * 16 + l15) * 64 + ((jp * 32 + quad * 8) ^ swz)]);
                o_acc[0][nd] = __builtin_amdgcn_mfma_f32_16x16x32_bf16(pf[0], vf, o_acc[0][nd], 0, 0, 0);
                o_acc[1][nd] = __builtin_amdgcn_mfma_f32_16x16x32_bf16(pf[1], vf, o_acc[1][nd], 0, 0, 0);
            }
            __builtin_amdgcn_s_setprio(0);
        }
        __syncthreads();   // drains prefetch vmcnt + orders reads before next overwrite
    }

    // row sums: lane holds partial for q-row l15; reduce across quads, then gather
    // the 4 rows (quad*4+r) this lane's o_acc covers via width-16 shfl.
#pragma unroll
    for (int hh = 0; hh < 2; hh++) {
        float ls = lsum[hh];
        ls += __shfl_xor(ls, 16);
        ls += __shfl_xor(ls, 32);
        float inv_l[4];
#pragma unroll
        for (int r = 0; r < 4; r++) inv_l[r] = 1.f / __shfl(ls, quad * 4 + r, 16);
#pragma unroll
        for (int nd = 0; nd < 8; nd++)
#pragma unroll
            for (int r = 0; r < 4; r++) {
                size_t row = qrowbase + wid * 16 + quad * 4 + r;
                int col = (h0 + hh) * HDIM + nd * 16 + l15;
                Ab[row * EMB + col] = f2bf(o_acc[hh][nd][r] * inv_l[r]);
            }
    }
}

extern "C" void kernel_launch(void* const* d_in, const int* in_sizes, int n_in,
                              void* d_out, int out_size, void* d_ws, size_t ws_size,
                              hipStream_t stream) {
    const float* x  = (const float*)d_in[0];
    const float* Wq = (const float*)d_in[1];
    const float* Wk = (const float*)d_in[2];
    const float* Wv = (const float*)d_in[3];
    const float* Wo = (const float*)d_in[4];
    const float* bo = (const float*)d_in[5];
    float* out = (float*)d_out;

    ushort* ws = (ushort*)d_ws;
    ushort* Xb    = ws;                              // [8192][2048]
    ushort* Wq_t  = Xb    + (size_t)MROWS * EMB;     // [2048][2048]
    ushort* Wkv_t = Wq_t  + (size_t)EMB * EMB;       // [256][2048]
    ushort* Wo_t  = Wkv_t + (size_t)256 * EMB;       // [2048][2048]
    ushort* Qb    = Wo_t  + (size_t)EMB * EMB;       // [8192][2048]
    ushort* Kb    = Qb    + (size_t)MROWS * EMB;     // [8192][128]
    ushort* Vg    = Kb    + (size_t)MROWS * HDIM;    // V^T [128][8192]
    ushort* Ab    = Vg    + (size_t)HDIM * MROWS;    // [8192][2048]

    cast_bf16_kernel<<<dim3(MROWS * EMB / 1024), 256, 0, stream>>>(x, Xb, MROWS * EMB);
    transpose_cast_kernel<<<dim3(EMB / 32, EMB / 32), dim3(32, 8), 0, stream>>>(Wq, Wq_t, EMB, EMB);
    transpose_cast_kernel<<<dim3(HDIM / 32, EMB / 32), dim3(32, 8), 0, stream>>>(Wk, Wkv_t, EMB, HDIM);
    transpose_cast_kernel<<<dim3(HDIM / 32, EMB / 32), dim3(32, 8), 0, stream>>>(Wv, Wkv_t + (size_t)HDIM * EMB, EMB, HDIM);
    transpose_cast_kernel<<<dim3(EMB / 32, EMB / 32), dim3(32, 8), 0, stream>>>(Wo, Wo_t, EMB, EMB);

    gemm_bt_kernel<0><<<dim3(EMB / 128, MROWS / 128), 256, 0, stream>>>(Xb, Wq_t, Qb, nullptr, nullptr, MROWS, EMB, EMB);
    gemm_bt_kernel<2><<<dim3(2, MROWS / 128), 256, 0, stream>>>(Xb, Wkv_t, Kb, Vg, nullptr, MROWS, 256, EMB);
    mqa_attn_kernel<<<dim3(QTILES, NHEADS / 2, BATCH), 256, 0, stream>>>(Qb, Kb, Vg, Ab);
    gemm_bt_kernel<1><<<dim3(EMB / 128, MROWS / 128), 256, 0, stream>>>(Ab, Wo_t, out, nullptr, bo, MROWS, EMB, EMB);
}

// Round 5
// 477.427 us; speedup vs baseline: 1.1710x; 1.1625x over previous
//
#include <hip/hip_runtime.h>
#include <stdint.h>

typedef __attribute__((ext_vector_type(8))) short short8;
typedef __attribute__((ext_vector_type(4))) float floatx4;

#define TLEN 2048
#define BATCH 4
#define EMB 2048
#define NHEADS 16
#define HDIM 128
#define MROWS (BATCH * TLEN) /* 8192 */
#define QTILES (TLEN / 64)   /* 32 */

struct TrueT  { static constexpr bool value = true;  };
struct FalseT { static constexpr bool value = false; };

__device__ __forceinline__ ushort f2bf(float f) {
    union { float f; uint32_t u; } v; v.f = f;
    uint32_t u = v.u;
    return (ushort)((u + 0x7fffu + ((u >> 16) & 1u)) >> 16);
}

__device__ __forceinline__ uint32_t cvt_pk_bf16(float a, float b) {
    uint32_t r;
    asm volatile("v_cvt_pk_bf16_f32 %0, %1, %2" : "=v"(r) : "v"(a), "v"(b));
    return r;
}

__device__ __forceinline__ void async_copy16(const ushort* g, ushort* l) {
    __builtin_amdgcn_global_load_lds(
        (const __attribute__((address_space(1))) uint32_t*)g,
        (__attribute__((address_space(3))) uint32_t*)l, 16, 0, 0);
}

// ---------------- cast fp32 -> bf16 ----------------
__global__ __launch_bounds__(256) void cast_bf16_kernel(const float* __restrict__ in,
                                                        ushort* __restrict__ out, int n) {
    int i = (blockIdx.x * 256 + threadIdx.x) * 4;
    if (i >= n) return;
    float4 f = *(const float4*)(in + i);
    ushort4 o;
    o.x = f2bf(f.x); o.y = f2bf(f.y); o.z = f2bf(f.z); o.w = f2bf(f.w);
    *(ushort4*)(out + i) = o;
}

// ---------------- transpose + cast: fp32 [R][Cc] -> bf16 [Cc][R] ----------------
__global__ void transpose_cast_kernel(const float* __restrict__ in, ushort* __restrict__ out,
                                      int R, int Cc) {
    __shared__ float tile[32][33];
    int x = blockIdx.x * 32 + threadIdx.x;
    int y0 = blockIdx.y * 32;
#pragma unroll
    for (int i = 0; i < 4; i++) {
        int y = y0 + threadIdx.y + i * 8;
        tile[threadIdx.y + i * 8][threadIdx.x] = in[(size_t)y * Cc + x];
    }
    __syncthreads();
    int xo = y0 + threadIdx.x;
#pragma unroll
    for (int i = 0; i < 4; i++) {
        int yo = blockIdx.x * 32 + threadIdx.y + i * 8;
        out[(size_t)yo * R + xo] = f2bf(tile[threadIdx.x][threadIdx.y + i * 8]);
    }
}

// ---------------- bf16 MFMA GEMM (m97 structure): C = A[M,K] * Bt[N,K]^T ----------------
// Default blockIdx mapping: at N=2048 each XCD naturally sees only 2 B col-panels (1MB,
// L2-resident). XCD-chunked swizzle measurably regressed this (round 3): do not swizzle.
template <int MODE>
__global__ __launch_bounds__(256) void gemm_bt_kernel(const ushort* __restrict__ A,
                                                      const ushort* __restrict__ Bt,
                                                      void* __restrict__ Cp,
                                                      void* __restrict__ Cp2,
                                                      const float* __restrict__ bias,
                                                      int M, int N, int K) {
    __shared__ ushort As[128 * 64];
    __shared__ ushort Bs[128 * 64];
    int tid = threadIdx.x;
    int wid = tid >> 6, lane = tid & 63;
    int quad = lane >> 4, l15 = lane & 15;
    int m0 = blockIdx.y * 128;
    int n0 = blockIdx.x * 128;
    int rm = (wid >> 1) * 64;
    int cn = (wid & 1) * 64;
    int grow = lane >> 3;       // 0..7
    int gcol = (lane & 7) * 8;  // 0..56

    floatx4 acc[4][4];
#pragma unroll
    for (int i = 0; i < 4; i++)
#pragma unroll
        for (int j = 0; j < 4; j++)
#pragma unroll
            for (int r = 0; r < 4; r++) acc[i][j][r] = 0.f;

    for (int kk = 0; kk < K; kk += 64) {
#pragma unroll
        for (int c = 0; c < 4; c++) {
            int chunk = wid * 4 + c;              // 0..15, wave-uniform
            int row = chunk * 8 + grow;
            async_copy16(A + (size_t)(m0 + row) * K + kk + gcol, &As[chunk * 512]);
            async_copy16(Bt + (size_t)(n0 + row) * K + kk + gcol, &Bs[chunk * 512]);
        }
        __syncthreads();
#pragma unroll
        for (int ks = 0; ks < 64; ks += 32) {
            short8 af[4], bf[4];
#pragma unroll
            for (int i = 0; i < 4; i++)
                af[i] = *(const short8*)(&As[(rm + i * 16 + l15) * 64 + ks + quad * 8]);
#pragma unroll
            for (int j = 0; j < 4; j++)
                bf[j] = *(const short8*)(&Bs[(cn + j * 16 + l15) * 64 + ks + quad * 8]);
#pragma unroll
            for (int i = 0; i < 4; i++)
#pragma unroll
                for (int j = 0; j < 4; j++)
                    acc[i][j] = __builtin_amdgcn_mfma_f32_16x16x32_bf16(af[i], bf[j], acc[i][j], 0, 0, 0);
        }
        __syncthreads();
    }
#pragma unroll
    for (int i = 0; i < 4; i++)
#pragma unroll
        for (int j = 0; j < 4; j++) {
            if (MODE == 2 && n0 != 0) {
                int d = cn + j * 16 + l15;
                int row = m0 + rm + i * 16 + quad * 4;
                ushort4 o;
                o.x = f2bf(acc[i][j][0]); o.y = f2bf(acc[i][j][1]);
                o.z = f2bf(acc[i][j][2]); o.w = f2bf(acc[i][j][3]);
                *(ushort4*)((ushort*)Cp2 + (size_t)d * M + row) = o;
            } else {
#pragma unroll
                for (int r = 0; r < 4; r++) {
                    int row = m0 + rm + i * 16 + quad * 4 + r;
                    int col = n0 + cn + j * 16 + l15;
                    float v = acc[i][j][r];
                    if (MODE == 0) {
                        ((ushort*)Cp)[(size_t)row * N + col] = f2bf(v);
                    } else if (MODE == 1) {
                        ((float*)Cp)[(size_t)row * N + col] = v + bias[col];
                    } else {
                        ((ushort*)Cp)[(size_t)row * HDIM + col] = f2bf(v);
                    }
                }
            }
        }
}

// ---------------- flash MQA attention: paired q-tiles, 2 heads, P in registers, KVBLK=128 ----
// grid: (QTILES/2, H/2, B) = 512 UNIFORM blocks (each pairs q-tiles {31-bx, bx} -> 17 tiles
// of 128 keys exactly). Round-3/4 analysis: the unpaired grid put SAME-qt blocks on each CU
// -> 1.9x CU load imbalance (Occupancy 11%). Uniform blocks fix the straggler CUs.
// KVBLK=128 single-buffered (round-3 winner), swizzled gload_lds staging, swapped QK^T +
// permlane32/16_swap in-register P. Causal mask peeled: only the final tile runs masked code.
__global__ __launch_bounds__(256, 2) void mqa_attn_kernel(const ushort* __restrict__ Qb,
                                                          const ushort* __restrict__ Kb,
                                                          const ushort* __restrict__ Vg,
                                                          ushort* __restrict__ Ab) {
    __shared__ ushort Ks[128 * 128];   // [key][d], XOR-swizzled cols (32KB)
    __shared__ ushort Vs[128 * 128];   // V^T [d][key], XOR-swizzled cols (32KB)
    int tid = threadIdx.x;
    int wid = tid >> 6, lane = tid & 63;
    int quad = lane >> 4, l15 = lane & 15;
    int h0 = blockIdx.y * 2, b = blockIdx.z;
    const float scale2 = 0.08838834764831845f * 1.4426950408889634f; // 1/sqrt(128)*log2(e)
    const ushort* kbase = Kb + (size_t)b * TLEN * HDIM;
    const ushort* vbase = Vg + (size_t)b * TLEN;

    int rowloc = wid * 16 + l15;   // q-row within the 64-row q-tile
    int swz = (l15 & 7) << 3;

    auto stage = [&](int jt) {
#pragma unroll
        for (int i = 0; i < 8; i++) {
            int c = wid * 8 + i;                             // chunk 0..31 (1KB each)
            int kr = c * 4 + quad;                           // K row in tile 0..127
            int kc = (l15 * 8) ^ ((kr & 7) << 3);            // swizzled ushort col
            async_copy16(kbase + (size_t)(jt * 128 + kr) * HDIM + kc, &Ks[c * 512]);
            int vd = c * 4 + quad;                           // V d-row 0..127
            int vc = (l15 * 8) ^ ((vd & 7) << 3);            // swizzled ushort col
            async_copy16(vbase + (size_t)vd * MROWS + jt * 128 + vc, &Vs[c * 512]);
        }
    };

#pragma unroll 1
    for (int t = 0; t < 2; t++) {
        int qt = (t == 0) ? (QTILES - 1 - blockIdx.x) : blockIdx.x;
        size_t qrowbase = (size_t)b * TLEN + qt * 64;
        int dlim = rowloc + ((qt & 1) ? 64 : 0);  // diag-tile local key limit
        bool evenqt = (qt & 1) == 0;
        int njt = qt / 2 + 1;                     // number of 128-key tiles

        // Q fragments in registers (reused across all jt)
        short8 aq[2][4];
#pragma unroll
        for (int hh = 0; hh < 2; hh++) {
            const ushort* qp = Qb + (qrowbase + wid * 16 + l15) * EMB + (h0 + hh) * HDIM + quad * 8;
#pragma unroll
            for (int kd = 0; kd < 4; kd++) aq[hh][kd] = *(const short8*)(qp + kd * 32);
        }

        float lsum[2] = {0.f, 0.f};
        floatx4 o_acc[2][8];
#pragma unroll
        for (int hh = 0; hh < 2; hh++)
#pragma unroll
            for (int nd = 0; nd < 8; nd++)
#pragma unroll
                for (int r = 0; r < 4; r++) o_acc[hh][nd][r] = 0.f;

        auto compute_tile = [&](auto mtag) {
            constexpr bool MASKED = decltype(mtag)::value;
#pragma unroll
            for (int jp = 0; jp < 4; jp++) {     // key chunk of 32: j in {2jp, 2jp+1}
                if (MASKED && evenqt && jp >= 2) continue;  // fully-masked upper half
                uint32_t XA[2][2], XB[2][2];     // [hh][jj] packed bf16 pairs
#pragma unroll
                for (int jj = 0; jj < 2; jj++) {
                    int j = jp * 2 + jj;
                    floatx4 s0, s1;
#pragma unroll
                    for (int r = 0; r < 4; r++) { s0[r] = 0.f; s1[r] = 0.f; }
                    __builtin_amdgcn_s_setprio(1);
#pragma unroll
                    for (int kd = 0; kd < 4; kd++) {
                        short8 ak = *(const short8*)(&Ks[(j * 16 + l15) * 128 + ((kd * 32 + quad * 8) ^ swz)]);
                        s0 = __builtin_amdgcn_mfma_f32_16x16x32_bf16(ak, aq[0][kd], s0, 0, 0, 0);
                        s1 = __builtin_amdgcn_mfma_f32_16x16x32_bf16(ak, aq[1][kd], s1, 0, 0, 0);
                    }
                    __builtin_amdgcn_s_setprio(0);
                    // softmax (fixed-max): e = exp2(s*scale2); mask only in the peeled tile
                    float e0[4], e1[4];
#pragma unroll
                    for (int r = 0; r < 4; r++) {
                        float v0 = exp2f(s0[r] * scale2);
                        float v1 = exp2f(s1[r] * scale2);
                        if constexpr (MASKED) {
                            int key = j * 16 + quad * 4 + r;
                            if (key > dlim) { v0 = 0.f; v1 = 0.f; }
                        }
                        e0[r] = v0; e1[r] = v1;
                        lsum[0] += v0; lsum[1] += v1;
                    }
                    XA[0][jj] = cvt_pk_bf16(e0[0], e0[1]); XB[0][jj] = cvt_pk_bf16(e0[2], e0[3]);
                    XA[1][jj] = cvt_pk_bf16(e1[0], e1[1]); XB[1][jj] = cvt_pk_bf16(e1[2], e1[3]);
                }
                // ---- cross-quad redistribution -> PV A-fragments (in-register) ----
                short8 pf[2];
#pragma unroll
                for (int hh = 0; hh < 2; hh++) {
                    uint32_t xA = XA[hh][0], yA = XA[hh][1];
                    uint32_t xB = XB[hh][0], yB = XB[hh][1];
                    asm volatile("v_permlane32_swap_b32 %0, %1" : "+v"(xA), "+v"(yA));
                    asm volatile("v_permlane16_swap_b32 %0, %1" : "+v"(xA), "+v"(yA));
                    asm volatile("v_permlane32_swap_b32 %0, %1" : "+v"(xB), "+v"(yB));
                    asm volatile("v_permlane16_swap_b32 %0, %1" : "+v"(xB), "+v"(yB));
                    union { uint32_t u[4]; short8 s; } fu;
                    fu.u[0] = xA; fu.u[1] = xB; fu.u[2] = yA; fu.u[3] = yB;
                    pf[hh] = fu.s;
                }
                // ---- O += P V for this 32-key chunk ----
                __builtin_amdgcn_s_setprio(1);
#pragma unroll
                for (int nd = 0; nd < 8; nd++) {
                    short8 vf = *(const short8*)(&Vs[(nd * 16 + l15) * 128 + ((jp * 32 + quad * 8) ^ swz)]);
                    o_acc[0][nd] = __builtin_amdgcn_mfma_f32_16x16x32_bf16(pf[0], vf, o_acc[0][nd], 0, 0, 0);
                    o_acc[1][nd] = __builtin_amdgcn_mfma_f32_16x16x32_bf16(pf[1], vf, o_acc[1][nd], 0, 0, 0);
                }
                __builtin_amdgcn_s_setprio(0);
            }
        };

#pragma unroll 1
        for (int jt = 0; jt < njt - 1; ++jt) {   // unmasked main tiles
            stage(jt);
            __syncthreads();
            compute_tile(FalseT{});
            __syncthreads();
        }
        {                                        // peeled final (diagonal) tile
            stage(njt - 1);
            __syncthreads();
            compute_tile(TrueT{});
            __syncthreads();
        }

        // row sums: lane holds partial for q-row l15; reduce across quads, then gather
        // the 4 rows (quad*4+r) this lane's o_acc covers via width-16 shfl.
#pragma unroll
        for (int hh = 0; hh < 2; hh++) {
            float ls = lsum[hh];
            ls += __shfl_xor(ls, 16);
            ls += __shfl_xor(ls, 32);
            float inv_l[4];
#pragma unroll
            for (int r = 0; r < 4; r++) inv_l[r] = 1.f / __shfl(ls, quad * 4 + r, 16);
#pragma unroll
            for (int nd = 0; nd < 8; nd++)
#pragma unroll
                for (int r = 0; r < 4; r++) {
                    size_t row = qrowbase + wid * 16 + quad * 4 + r;
                    int col = (h0 + hh) * HDIM + nd * 16 + l15;
                    Ab[row * EMB + col] = f2bf(o_acc[hh][nd][r] * inv_l[r]);
                }
        }
    }
}

extern "C" void kernel_launch(void* const* d_in, const int* in_sizes, int n_in,
                              void* d_out, int out_size, void* d_ws, size_t ws_size,
                              hipStream_t stream) {
    const float* x  = (const float*)d_in[0];
    const float* Wq = (const float*)d_in[1];
    const float* Wk = (const float*)d_in[2];
    const float* Wv = (const float*)d_in[3];
    const float* Wo = (const float*)d_in[4];
    const float* bo = (const float*)d_in[5];
    float* out = (float*)d_out;

    ushort* ws = (ushort*)d_ws;
    ushort* Xb    = ws;                              // [8192][2048]
    ushort* Wq_t  = Xb    + (size_t)MROWS * EMB;     // [2048][2048]
    ushort* Wkv_t = Wq_t  + (size_t)EMB * EMB;       // [256][2048]
    ushort* Wo_t  = Wkv_t + (size_t)256 * EMB;       // [2048][2048]
    ushort* Qb    = Wo_t  + (size_t)EMB * EMB;       // [8192][2048]
    ushort* Kb    = Qb    + (size_t)MROWS * EMB;     // [8192][128]
    ushort* Vg    = Kb    + (size_t)MROWS * HDIM;    // V^T [128][8192]
    ushort* Ab    = Vg    + (size_t)HDIM * MROWS;    // [8192][2048]

    cast_bf16_kernel<<<dim3(MROWS * EMB / 1024), 256, 0, stream>>>(x, Xb, MROWS * EMB);
    transpose_cast_kernel<<<dim3(EMB / 32, EMB / 32), dim3(32, 8), 0, stream>>>(Wq, Wq_t, EMB, EMB);
    transpose_cast_kernel<<<dim3(HDIM / 32, EMB / 32), dim3(32, 8), 0, stream>>>(Wk, Wkv_t, EMB, HDIM);
    transpose_cast_kernel<<<dim3(HDIM / 32, EMB / 32), dim3(32, 8), 0, stream>>>(Wv, Wkv_t + (size_t)HDIM * EMB, EMB, HDIM);
    transpose_cast_kernel<<<dim3(EMB / 32, EMB / 32), dim3(32, 8), 0, stream>>>(Wo, Wo_t, EMB, EMB);

    gemm_bt_kernel<0><<<dim3(EMB / 128, MROWS / 128), 256, 0, stream>>>(Xb, Wq_t, Qb, nullptr, nullptr, MROWS, EMB, EMB);
    gemm_bt_kernel<2><<<dim3(2, MROWS / 128), 256, 0, stream>>>(Xb, Wkv_t, Kb, Vg, nullptr, MROWS, 256, EMB);
    mqa_attn_kernel<<<dim3(QTILES / 2, NHEADS / 2, BATCH), 256, 0, stream>>>(Qb, Kb, Vg, Ab);
    gemm_bt_kernel<1><<<dim3(EMB / 128, MROWS / 128), 256, 0, stream>>>(Ab, Wo_t, out, nullptr, bo, MROWS, EMB, EMB);
}

// Round 6
// 468.285 us; speedup vs baseline: 1.1939x; 1.0195x over previous
//
#include <hip/hip_runtime.h>
#include <stdint.h>

typedef __attribute__((ext_vector_type(8))) short short8;
typedef __attribute__((ext_vector_type(4))) float floatx4;

#define TLEN 2048
#define BATCH 4
#define EMB 2048
#define NHEADS 16
#define HDIM 128
#define MROWS (BATCH * TLEN) /* 8192 */
#define QTILES (TLEN / 64)   /* 32 */

struct TrueT  { static constexpr bool value = true;  };
struct FalseT { static constexpr bool value = false; };

__device__ __forceinline__ ushort f2bf(float f) {
    union { float f; uint32_t u; } v; v.f = f;
    uint32_t u = v.u;
    return (ushort)((u + 0x7fffu + ((u >> 16) & 1u)) >> 16);
}

__device__ __forceinline__ uint32_t cvt_pk_bf16(float a, float b) {
    uint32_t r;
    asm volatile("v_cvt_pk_bf16_f32 %0, %1, %2" : "=v"(r) : "v"(a), "v"(b));
    return r;
}

__device__ __forceinline__ void async_copy16(const ushort* g, ushort* l) {
    __builtin_amdgcn_global_load_lds(
        (const __attribute__((address_space(1))) uint32_t*)g,
        (__attribute__((address_space(3))) uint32_t*)l, 16, 0, 0);
}

// ---------------- cast fp32 -> bf16 ----------------
__global__ __launch_bounds__(256) void cast_bf16_kernel(const float* __restrict__ in,
                                                        ushort* __restrict__ out, int n) {
    int i = (blockIdx.x * 256 + threadIdx.x) * 4;
    if (i >= n) return;
    float4 f = *(const float4*)(in + i);
    ushort4 o;
    o.x = f2bf(f.x); o.y = f2bf(f.y); o.z = f2bf(f.z); o.w = f2bf(f.w);
    *(ushort4*)(out + i) = o;
}

// ---------------- transpose + cast: fp32 [R][Cc] -> bf16 [Cc][R] ----------------
__global__ void transpose_cast_kernel(const float* __restrict__ in, ushort* __restrict__ out,
                                      int R, int Cc) {
    __shared__ float tile[32][33];
    int x = blockIdx.x * 32 + threadIdx.x;
    int y0 = blockIdx.y * 32;
#pragma unroll
    for (int i = 0; i < 4; i++) {
        int y = y0 + threadIdx.y + i * 8;
        tile[threadIdx.y + i * 8][threadIdx.x] = in[(size_t)y * Cc + x];
    }
    __syncthreads();
    int xo = y0 + threadIdx.x;
#pragma unroll
    for (int i = 0; i < 4; i++) {
        int yo = blockIdx.x * 32 + threadIdx.y + i * 8;
        out[(size_t)yo * R + xo] = f2bf(tile[threadIdx.x][threadIdx.y + i * 8]);
    }
}

// ---------------- bf16 MFMA GEMM (m97 structure, 128x128): kept for the KV projection ----
// MODE 2: KV split (K normal / V transposed-packed).
template <int MODE>
__global__ __launch_bounds__(256) void gemm_bt_kernel(const ushort* __restrict__ A,
                                                      const ushort* __restrict__ Bt,
                                                      void* __restrict__ Cp,
                                                      void* __restrict__ Cp2,
                                                      const float* __restrict__ bias,
                                                      int M, int N, int K) {
    __shared__ ushort As[128 * 64];
    __shared__ ushort Bs[128 * 64];
    int tid = threadIdx.x;
    int wid = tid >> 6, lane = tid & 63;
    int quad = lane >> 4, l15 = lane & 15;
    int m0 = blockIdx.y * 128;
    int n0 = blockIdx.x * 128;
    int rm = (wid >> 1) * 64;
    int cn = (wid & 1) * 64;
    int grow = lane >> 3;       // 0..7
    int gcol = (lane & 7) * 8;  // 0..56

    floatx4 acc[4][4];
#pragma unroll
    for (int i = 0; i < 4; i++)
#pragma unroll
        for (int j = 0; j < 4; j++)
#pragma unroll
            for (int r = 0; r < 4; r++) acc[i][j][r] = 0.f;

    for (int kk = 0; kk < K; kk += 64) {
#pragma unroll
        for (int c = 0; c < 4; c++) {
            int chunk = wid * 4 + c;              // 0..15, wave-uniform
            int row = chunk * 8 + grow;
            async_copy16(A + (size_t)(m0 + row) * K + kk + gcol, &As[chunk * 512]);
            async_copy16(Bt + (size_t)(n0 + row) * K + kk + gcol, &Bs[chunk * 512]);
        }
        __syncthreads();
#pragma unroll
        for (int ks = 0; ks < 64; ks += 32) {
            short8 af[4], bf[4];
#pragma unroll
            for (int i = 0; i < 4; i++)
                af[i] = *(const short8*)(&As[(rm + i * 16 + l15) * 64 + ks + quad * 8]);
#pragma unroll
            for (int j = 0; j < 4; j++)
                bf[j] = *(const short8*)(&Bs[(cn + j * 16 + l15) * 64 + ks + quad * 8]);
#pragma unroll
            for (int i = 0; i < 4; i++)
#pragma unroll
                for (int j = 0; j < 4; j++)
                    acc[i][j] = __builtin_amdgcn_mfma_f32_16x16x32_bf16(af[i], bf[j], acc[i][j], 0, 0, 0);
        }
        __syncthreads();
    }
#pragma unroll
    for (int i = 0; i < 4; i++)
#pragma unroll
        for (int j = 0; j < 4; j++) {
            if (MODE == 2 && n0 != 0) {
                int d = cn + j * 16 + l15;
                int row = m0 + rm + i * 16 + quad * 4;
                ushort4 o;
                o.x = f2bf(acc[i][j][0]); o.y = f2bf(acc[i][j][1]);
                o.z = f2bf(acc[i][j][2]); o.w = f2bf(acc[i][j][3]);
                *(ushort4*)((ushort*)Cp2 + (size_t)d * M + row) = o;
            } else {
#pragma unroll
                for (int r = 0; r < 4; r++) {
                    int row = m0 + rm + i * 16 + quad * 4 + r;
                    int col = n0 + cn + j * 16 + l15;
                    float v = acc[i][j][r];
                    if (MODE == 0) {
                        ((ushort*)Cp)[(size_t)row * N + col] = f2bf(v);
                    } else if (MODE == 1) {
                        ((float*)Cp)[(size_t)row * N + col] = v + bias[col];
                    } else {
                        ((ushort*)Cp)[(size_t)row * HDIM + col] = f2bf(v);
                    }
                }
            }
        }
}

// ---------------- 256x256 bf16 GEMM, 8 waves, BK=32, 3-slot rotating pipeline --------------
// C = A[M,K] * Bt[N,K]^T. Iteration t: compute slot t%3; stage tile t+2 into slot (t+2)%3
// (that slot's readers finished a full tile ago -> no race). Counted s_waitcnt vmcnt(4) +
// RAW s_barrier per tile: tile t+1 guaranteed landed, tile t+2's 4 loads stay in flight
// across the barrier (never drains in main loop; __syncthreads would emit vmcnt(0)).
// T2 swizzle: read col-group quad ^ ((l15 ^ l15>>2)&3) -> 16-lane groups hit 8 disjoint
// 4-bank spans = conflict-free; gload_lds dest stays linear, global SOURCE col pre-swizzled
// with the same involution. T5 setprio around the 32-MFMA cluster.
// MODE 0: bf16 out. MODE 1: fp32 out + bias.
template <int MODE>
__global__ __launch_bounds__(512, 2) void gemm256_kernel(const ushort* __restrict__ A,
                                                         const ushort* __restrict__ Bt,
                                                         void* __restrict__ Cp,
                                                         const float* __restrict__ bias,
                                                         int M, int N, int K) {
    __shared__ ushort As[3][256 * 32];   // [slot][row][kcol] 16KB each
    __shared__ ushort Bs[3][256 * 32];
    int tid = threadIdx.x;
    int wid = tid >> 6, lane = tid & 63;
    int quad = lane >> 4, l15 = lane & 15;
    int wr = wid >> 2, wc = wid & 3;     // 2 x 4 wave grid; per-wave output 128x64
    int m0 = blockIdx.y * 256, n0 = blockIdx.x * 256;

    // staging: 16 chunks/operand, chunk = 16 rows x 32 cols (1KB). wave w: chunks {2w, 2w+1}.
    // lane l -> row (l>>2), colgroup (l&3); source col pre-swizzled (involution with read).
    int srow = lane >> 2;                                            // 0..15
    int scol = (((lane & 3) ^ ((lane >> 2) & 3) ^ ((lane >> 4) & 3))) * 8;
    // read swizzle: colgroup = quad ^ ((l15 ^ (l15>>2)) & 3)
    int rdsw = (quad ^ ((l15 ^ (l15 >> 2)) & 3)) * 8;

    floatx4 acc[8][4];
#pragma unroll
    for (int m = 0; m < 8; m++)
#pragma unroll
        for (int n = 0; n < 4; n++)
#pragma unroll
            for (int r = 0; r < 4; r++) acc[m][n][r] = 0.f;

    auto stage = [&](int t) {
        int slot = t % 3;
        int kk = t * 32;
#pragma unroll
        for (int i = 0; i < 2; i++) {
            int c = wid * 2 + i;                 // 0..15, wave-uniform
            int row = c * 16 + srow;
            async_copy16(A + (size_t)(m0 + row) * K + kk + scol, &As[slot][c * 512]);
            async_copy16(Bt + (size_t)(n0 + row) * K + kk + scol, &Bs[slot][c * 512]);
        }
    };

    auto compute = [&](int t) {
        int slot = t % 3;
        const ushort* as = &As[slot][0];
        const ushort* bs = &Bs[slot][0];
        short8 af[8], bf[4];
#pragma unroll
        for (int m = 0; m < 8; m++)
            af[m] = *(const short8*)(&as[(wr * 128 + m * 16 + l15) * 32 + rdsw]);
#pragma unroll
        for (int n = 0; n < 4; n++)
            bf[n] = *(const short8*)(&bs[(wc * 64 + n * 16 + l15) * 32 + rdsw]);
        __builtin_amdgcn_s_setprio(1);
#pragma unroll
        for (int m = 0; m < 8; m++)
#pragma unroll
            for (int n = 0; n < 4; n++)
                acc[m][n] = __builtin_amdgcn_mfma_f32_16x16x32_bf16(af[m], bf[n], acc[m][n], 0, 0, 0);
        __builtin_amdgcn_s_setprio(0);
    };

    int NT = K >> 5;   // 64 for K=2048

    stage(0);
    stage(1);
    asm volatile("s_waitcnt vmcnt(4)" ::: "memory");   // tile 0 landed; tile 1 in flight
    __builtin_amdgcn_s_barrier();

#pragma unroll 1
    for (int t = 0; t < NT - 2; ++t) {
        stage(t + 2);                                   // issue early, overlaps compute
        compute(t);
        asm volatile("s_waitcnt vmcnt(4)" ::: "memory"); // tile t+1 landed; t+2 in flight
        __builtin_amdgcn_s_barrier();
    }
    compute(NT - 2);
    asm volatile("s_waitcnt vmcnt(0)" ::: "memory");    // final drain (epilogue only)
    __builtin_amdgcn_s_barrier();
    compute(NT - 1);

    // epilogue: C = acc (+bias)
#pragma unroll
    for (int m = 0; m < 8; m++)
#pragma unroll
        for (int n = 0; n < 4; n++)
#pragma unroll
            for (int r = 0; r < 4; r++) {
                int row = m0 + wr * 128 + m * 16 + quad * 4 + r;
                int col = n0 + wc * 64 + n * 16 + l15;
                float v = acc[m][n][r];
                if (MODE == 0) {
                    ((ushort*)Cp)[(size_t)row * N + col] = f2bf(v);
                } else {
                    ((float*)Cp)[(size_t)row * N + col] = v + bias[col];
                }
            }
}

// ---------------- flash MQA attention: paired q-tiles, 2 heads, P in registers, KVBLK=128 ----
// grid: (QTILES/2, H/2, B) = 512 UNIFORM blocks (q-tiles {31-bx, bx} -> 17 tiles each).
__global__ __launch_bounds__(256, 2) void mqa_attn_kernel(const ushort* __restrict__ Qb,
                                                          const ushort* __restrict__ Kb,
                                                          const ushort* __restrict__ Vg,
                                                          ushort* __restrict__ Ab) {
    __shared__ ushort Ks[128 * 128];   // [key][d], XOR-swizzled cols (32KB)
    __shared__ ushort Vs[128 * 128];   // V^T [d][key], XOR-swizzled cols (32KB)
    int tid = threadIdx.x;
    int wid = tid >> 6, lane = tid & 63;
    int quad = lane >> 4, l15 = lane & 15;
    int h0 = blockIdx.y * 2, b = blockIdx.z;
    const float scale2 = 0.08838834764831845f * 1.4426950408889634f; // 1/sqrt(128)*log2(e)
    const ushort* kbase = Kb + (size_t)b * TLEN * HDIM;
    const ushort* vbase = Vg + (size_t)b * TLEN;

    int rowloc = wid * 16 + l15;   // q-row within the 64-row q-tile
    int swz = (l15 & 7) << 3;

    auto stage = [&](int jt) {
#pragma unroll
        for (int i = 0; i < 8; i++) {
            int c = wid * 8 + i;                             // chunk 0..31 (1KB each)
            int kr = c * 4 + quad;                           // K row in tile 0..127
            int kc = (l15 * 8) ^ ((kr & 7) << 3);            // swizzled ushort col
            async_copy16(kbase + (size_t)(jt * 128 + kr) * HDIM + kc, &Ks[c * 512]);
            int vd = c * 4 + quad;                           // V d-row 0..127
            int vc = (l15 * 8) ^ ((vd & 7) << 3);            // swizzled ushort col
            async_copy16(vbase + (size_t)vd * MROWS + jt * 128 + vc, &Vs[c * 512]);
        }
    };

#pragma unroll 1
    for (int t = 0; t < 2; t++) {
        int qt = (t == 0) ? (QTILES - 1 - blockIdx.x) : blockIdx.x;
        size_t qrowbase = (size_t)b * TLEN + qt * 64;
        int dlim = rowloc + ((qt & 1) ? 64 : 0);  // diag-tile local key limit
        bool evenqt = (qt & 1) == 0;
        int njt = qt / 2 + 1;                     // number of 128-key tiles

        // Q fragments in registers (reused across all jt)
        short8 aq[2][4];
#pragma unroll
        for (int hh = 0; hh < 2; hh++) {
            const ushort* qp = Qb + (qrowbase + wid * 16 + l15) * EMB + (h0 + hh) * HDIM + quad * 8;
#pragma unroll
            for (int kd = 0; kd < 4; kd++) aq[hh][kd] = *(const short8*)(qp + kd * 32);
        }

        float lsum[2] = {0.f, 0.f};
        floatx4 o_acc[2][8];
#pragma unroll
        for (int hh = 0; hh < 2; hh++)
#pragma unroll
            for (int nd = 0; nd < 8; nd++)
#pragma unroll
                for (int r = 0; r < 4; r++) o_acc[hh][nd][r] = 0.f;

        auto compute_tile = [&](auto mtag) {
            constexpr bool MASKED = decltype(mtag)::value;
#pragma unroll
            for (int jp = 0; jp < 4; jp++) {     // key chunk of 32: j in {2jp, 2jp+1}
                if (MASKED && evenqt && jp >= 2) continue;  // fully-masked upper half
                uint32_t XA[2][2], XB[2][2];     // [hh][jj] packed bf16 pairs
#pragma unroll
                for (int jj = 0; jj < 2; jj++) {
                    int j = jp * 2 + jj;
                    floatx4 s0, s1;
#pragma unroll
                    for (int r = 0; r < 4; r++) { s0[r] = 0.f; s1[r] = 0.f; }
                    __builtin_amdgcn_s_setprio(1);
#pragma unroll
                    for (int kd = 0; kd < 4; kd++) {
                        short8 ak = *(const short8*)(&Ks[(j * 16 + l15) * 128 + ((kd * 32 + quad * 8) ^ swz)]);
                        s0 = __builtin_amdgcn_mfma_f32_16x16x32_bf16(ak, aq[0][kd], s0, 0, 0, 0);
                        s1 = __builtin_amdgcn_mfma_f32_16x16x32_bf16(ak, aq[1][kd], s1, 0, 0, 0);
                    }
                    __builtin_amdgcn_s_setprio(0);
                    // softmax (fixed-max): e = exp2(s*scale2); mask only in the peeled tile
                    float e0[4], e1[4];
#pragma unroll
                    for (int r = 0; r < 4; r++) {
                        float v0 = exp2f(s0[r] * scale2);
                        float v1 = exp2f(s1[r] * scale2);
                        if constexpr (MASKED) {
                            int key = j * 16 + quad * 4 + r;
                            if (key > dlim) { v0 = 0.f; v1 = 0.f; }
                        }
                        e0[r] = v0; e1[r] = v1;
                        lsum[0] += v0; lsum[1] += v1;
                    }
                    XA[0][jj] = cvt_pk_bf16(e0[0], e0[1]); XB[0][jj] = cvt_pk_bf16(e0[2], e0[3]);
                    XA[1][jj] = cvt_pk_bf16(e1[0], e1[1]); XB[1][jj] = cvt_pk_bf16(e1[2], e1[3]);
                }
                // ---- cross-quad redistribution -> PV A-fragments (in-register) ----
                short8 pf[2];
#pragma unroll
                for (int hh = 0; hh < 2; hh++) {
                    uint32_t xA = XA[hh][0], yA = XA[hh][1];
                    uint32_t xB = XB[hh][0], yB = XB[hh][1];
                    asm volatile("v_permlane32_swap_b32 %0, %1" : "+v"(xA), "+v"(yA));
                    asm volatile("v_permlane16_swap_b32 %0, %1" : "+v"(xA), "+v"(yA));
                    asm volatile("v_permlane32_swap_b32 %0, %1" : "+v"(xB), "+v"(yB));
                    asm volatile("v_permlane16_swap_b32 %0, %1" : "+v"(xB), "+v"(yB));
                    union { uint32_t u[4]; short8 s; } fu;
                    fu.u[0] = xA; fu.u[1] = xB; fu.u[2] = yA; fu.u[3] = yB;
                    pf[hh] = fu.s;
                }
                // ---- O += P V for this 32-key chunk ----
                __builtin_amdgcn_s_setprio(1);
#pragma unroll
                for (int nd = 0; nd < 8; nd++) {
                    short8 vf = *(const short8*)(&Vs[(nd * 16 + l15) * 128 + ((jp * 32 + quad * 8) ^ swz)]);
                    o_acc[0][nd] = __builtin_amdgcn_mfma_f32_16x16x32_bf16(pf[0], vf, o_acc[0][nd], 0, 0, 0);
                    o_acc[1][nd] = __builtin_amdgcn_mfma_f32_16x16x32_bf16(pf[1], vf, o_acc[1][nd], 0, 0, 0);
                }
                __builtin_amdgcn_s_setprio(0);
            }
        };

#pragma unroll 1
        for (int jt = 0; jt < njt - 1; ++jt) {   // unmasked main tiles
            stage(jt);
            __syncthreads();
            compute_tile(FalseT{});
            __syncthreads();
        }
        {                                        // peeled final (diagonal) tile
            stage(njt - 1);
            __syncthreads();
            compute_tile(TrueT{});
            __syncthreads();
        }

        // row sums: lane holds partial for q-row l15; reduce across quads, then gather
        // the 4 rows (quad*4+r) this lane's o_acc covers via width-16 shfl.
#pragma unroll
        for (int hh = 0; hh < 2; hh++) {
            float ls = lsum[hh];
            ls += __shfl_xor(ls, 16);
            ls += __shfl_xor(ls, 32);
            float inv_l[4];
#pragma unroll
            for (int r = 0; r < 4; r++) inv_l[r] = 1.f / __shfl(ls, quad * 4 + r, 16);
#pragma unroll
            for (int nd = 0; nd < 8; nd++)
#pragma unroll
                for (int r = 0; r < 4; r++) {
                    size_t row = qrowbase + wid * 16 + quad * 4 + r;
                    int col = (h0 + hh) * HDIM + nd * 16 + l15;
                    Ab[row * EMB + col] = f2bf(o_acc[hh][nd][r] * inv_l[r]);
                }
        }
    }
}

extern "C" void kernel_launch(void* const* d_in, const int* in_sizes, int n_in,
                              void* d_out, int out_size, void* d_ws, size_t ws_size,
                              hipStream_t stream) {
    const float* x  = (const float*)d_in[0];
    const float* Wq = (const float*)d_in[1];
    const float* Wk = (const float*)d_in[2];
    const float* Wv = (const float*)d_in[3];
    const float* Wo = (const float*)d_in[4];
    const float* bo = (const float*)d_in[5];
    float* out = (float*)d_out;

    ushort* ws = (ushort*)d_ws;
    ushort* Xb    = ws;                              // [8192][2048]
    ushort* Wq_t  = Xb    + (size_t)MROWS * EMB;     // [2048][2048]
    ushort* Wkv_t = Wq_t  + (size_t)EMB * EMB;       // [256][2048]
    ushort* Wo_t  = Wkv_t + (size_t)256 * EMB;       // [2048][2048]
    ushort* Qb    = Wo_t  + (size_t)EMB * EMB;       // [8192][2048]
    ushort* Kb    = Qb    + (size_t)MROWS * EMB;     // [8192][128]
    ushort* Vg    = Kb    + (size_t)MROWS * HDIM;    // V^T [128][8192]
    ushort* Ab    = Vg    + (size_t)HDIM * MROWS;    // [8192][2048]

    cast_bf16_kernel<<<dim3(MROWS * EMB / 1024), 256, 0, stream>>>(x, Xb, MROWS * EMB);
    transpose_cast_kernel<<<dim3(EMB / 32, EMB / 32), dim3(32, 8), 0, stream>>>(Wq, Wq_t, EMB, EMB);
    transpose_cast_kernel<<<dim3(HDIM / 32, EMB / 32), dim3(32, 8), 0, stream>>>(Wk, Wkv_t, EMB, HDIM);
    transpose_cast_kernel<<<dim3(HDIM / 32, EMB / 32), dim3(32, 8), 0, stream>>>(Wv, Wkv_t + (size_t)HDIM * EMB, EMB, HDIM);
    transpose_cast_kernel<<<dim3(EMB / 32, EMB / 32), dim3(32, 8), 0, stream>>>(Wo, Wo_t, EMB, EMB);

    gemm256_kernel<0><<<dim3(EMB / 256, MROWS / 256), 512, 0, stream>>>(Xb, Wq_t, Qb, nullptr, MROWS, EMB, EMB);
    gemm_bt_kernel<2><<<dim3(2, MROWS / 128), 256, 0, stream>>>(Xb, Wkv_t, Kb, Vg, nullptr, MROWS, 256, EMB);
    mqa_attn_kernel<<<dim3(QTILES / 2, NHEADS / 2, BATCH), 256, 0, stream>>>(Qb, Kb, Vg, Ab);
    gemm256_kernel<1><<<dim3(EMB / 256, MROWS / 256), 512, 0, stream>>>(Ab, Wo_t, out, bo, MROWS, EMB, EMB);
}